// Round 5
// baseline (344.765 us; speedup 1.0000x reference)
//
#include <hip/hip_runtime.h>
#include <hip/hip_bf16.h>

typedef __attribute__((ext_vector_type(4))) float f32x4;
typedef __attribute__((ext_vector_type(16))) float f32x16;
typedef __attribute__((ext_vector_type(2))) unsigned int u32x2;
typedef __attribute__((ext_vector_type(4))) unsigned int u32x4;
typedef __attribute__((ext_vector_type(8))) __bf16 bf16x8;

// fp32 -> bf16 via HW cvt (RTNE)
__device__ inline unsigned short f2bf(float x) {
    return __builtin_bit_cast(unsigned short, (__bf16)x);
}
__device__ inline unsigned int pack2(float lo, float hi) {
    return (unsigned int)f2bf(lo) | ((unsigned int)f2bf(hi) << 16);
}
// load 8 fp32, convert to 8 packed bf16 (16B)
__device__ inline u32x4 cvt8(const float* __restrict__ p) {
    f32x4 a = *(const f32x4*)p;
    f32x4 b = *(const f32x4*)(p + 4);
    u32x4 r;
    r[0] = pack2(a[0], a[1]);
    r[1] = pack2(a[2], a[3]);
    r[2] = pack2(b[0], b[1]);
    r[3] = pack2(b[2], b[3]);
    return r;
}
__device__ inline bf16x8 ldfrag(const unsigned short* p) {
    u32x4 t = *(const u32x4*)p;
    return __builtin_bit_cast(bf16x8, t);
}

// C[M=8192][N=1024] = A[8192][1024] * B[1024][1024]^T, epilogue variants.
// AF32: A is fp32 (convert during staging), else bf16 (ushort).
// MODE 0: bf16 output (acc+bias)*alpha, row-major [token][d]
// MODE 1: fp32 output acc+bias+resid (output projection)
// MODE 2: bf16 output acc+bias, transposed per-head [b*16+h][dh][key'],
//         with key' = key with bits 2<->3 swapped (pre-permuted for attn PV
//         fragment order; the swap maps aligned 4-key runs to aligned runs).
template<bool AF32, int MODE>
__global__ __launch_bounds__(256) void gemm_bt(
    const void* __restrict__ Ap, const float* __restrict__ Bw,
    const float* __restrict__ bias, const float* __restrict__ resid,
    void* __restrict__ Cp, float alpha)
{
    __shared__ unsigned short Al[128][40];   // pad 32->40 (80B stride: 2-way = free)
    __shared__ unsigned short Bl[128][40];
    const int tid = threadIdx.x;
    const int lane = tid & 63, w = tid >> 6;
    const int wr = w >> 1, wc = w & 1;
    const int m0 = blockIdx.x * 128, n0 = blockIdx.y * 128;
    const int fr = lane & 15, fq = lane >> 4;

    f32x4 acc[4][4] = {};

    for (int k0 = 0; k0 < 1024; k0 += 32) {
#pragma unroll
        for (int i = 0; i < 2; ++i) {
            int e = (i * 256 + tid) * 8;
            int r = e >> 5, c = e & 31;
            u32x4 av;
            if (AF32) av = cvt8((const float*)Ap + (size_t)(m0 + r) * 1024 + k0 + c);
            else {
                u32x4 t = *(const u32x4*)((const unsigned short*)Ap + (size_t)(m0 + r) * 1024 + k0 + c);
                av = t;
            }
            *(u32x4*)&Al[r][c] = av;
            u32x4 bv = cvt8(Bw + (size_t)(n0 + r) * 1024 + k0 + c);
            *(u32x4*)&Bl[r][c] = bv;
        }
        __syncthreads();
        bf16x8 af[4], bfv[4];
#pragma unroll
        for (int mt = 0; mt < 4; ++mt)
            af[mt] = ldfrag(&Al[wr * 64 + mt * 16 + fr][8 * fq]);
#pragma unroll
        for (int nt = 0; nt < 4; ++nt)
            bfv[nt] = ldfrag(&Bl[wc * 64 + nt * 16 + fr][8 * fq]);
#pragma unroll
        for (int mt = 0; mt < 4; ++mt)
#pragma unroll
            for (int nt = 0; nt < 4; ++nt)
                acc[mt][nt] = __builtin_amdgcn_mfma_f32_16x16x32_bf16(af[mt], bfv[nt], acc[mt][nt], 0, 0, 0);
        __syncthreads();
    }

#pragma unroll
    for (int mt = 0; mt < 4; ++mt) {
#pragma unroll
        for (int nt = 0; nt < 4; ++nt) {
            const int col = n0 + wc * 64 + nt * 16 + fr;
            const float bb = bias[col];
            const int row0 = m0 + wr * 64 + mt * 16 + fq * 4;
            if (MODE == 2) {
                // V^T with key bits 2<->3 swapped: 4 consecutive keys -> 8B
                float v0 = acc[mt][nt][0] + bb, v1 = acc[mt][nt][1] + bb;
                float v2 = acc[mt][nt][2] + bb, v3 = acc[mt][nt][3] + bb;
                const int bb_ = row0 >> 11, key = row0 & 2047;
                const int key2 = (key & ~12) | ((key & 4) << 1) | ((key & 8) >> 1);
                const size_t idx = ((size_t)bb_ * 1024 + col) * 2048 + key2;
                u32x2 pv;
                pv[0] = pack2(v0, v1);
                pv[1] = pack2(v2, v3);
                *(u32x2*)((unsigned short*)Cp + idx) = pv;
            } else {
#pragma unroll
                for (int r = 0; r < 4; ++r) {
                    const size_t idx = (size_t)(row0 + r) * 1024 + col;
                    float v = (acc[mt][nt][r] + bb) * alpha;
                    if (MODE == 1) ((float*)Cp)[idx] = v + resid[idx];
                    else           ((unsigned short*)Cp)[idx] = f2bf(v);
                }
            }
        }
    }
}

// Flash attention, 32x32 MFMA, swapped QK^T, softmax fully in registers.
// Q pre-scaled by log2(e)/sqrt(DH); mask additive in log2 domain.
// Block = 4 waves x 32 q-rows = 128 q-rows; KVBLK = 64.
// QK^T: mfma(A=K, B=Q) -> C[key][q]: q = lane&31, key = (r&3)+8*(r>>2)+4*hi.
// PV A-fragment = lane's own packed P words (V stored key-bit-2/3-permuted,
// so no cross-lane P redistribution is needed at all).
// LDS swizzle key: ((row ^ (row>>3)) & 7) -> fragment reads (rows x,x+8,x+16,
// x+24 together) land on distinct 16B slots: 2 lanes/bank = conflict-free.
__global__ __launch_bounds__(256) void attn_fwd(
    const unsigned short* __restrict__ Q, const unsigned short* __restrict__ K,
    const unsigned short* __restrict__ Vt_g, const int* __restrict__ mask,
    unsigned short* __restrict__ O)
{
    __shared__ unsigned short Kl[64][64];   // [key][dh], XOR-swizzled
    __shared__ unsigned short Vl[64][64];   // [dh][key'], XOR-swizzled
    __shared__ float mlf[64];
    __shared__ float lsq[128];              // per-wave 32 reciprocal denominators
    const int tid = threadIdx.x, lane = tid & 63, w = tid >> 6;
    const int l31 = lane & 31, hi = lane >> 5;
    const int q0 = blockIdx.x * 128;
    const int b = blockIdx.y >> 4;
    const size_t rowbase = (size_t)b * 2048;
    const int hoff = (blockIdx.y & 15) * 64;
    const size_t vbase = (size_t)blockIdx.y * 64 * 2048;

    // swizzle keys for fragment-read rows r = t*32 + l31 (t = 0,1)
    const int sw0 = (((l31) ^ (l31 >> 3)) & 7) << 3;
    const int sw1 = (((l31) ^ ((l31 >> 3) + 4)) & 7) << 3;

    // Q fragments (B-operand): lane holds Q[q0+w*32+l31][kk*16 + hi*8 + j]
    bf16x8 aq[4];
    {
        const unsigned short* qp = Q + (rowbase + q0 + w * 32 + l31) * 1024 + hoff + hi * 8;
#pragma unroll
        for (int kk = 0; kk < 4; ++kk) aq[kk] = ldfrag(qp + kk * 16);
    }
    f32x16 o[2] = {};
    float lsum = 0.f;

    for (int kb = 0; kb < 2048; kb += 64) {
        // stage K [64key][64dh] + permuted V^T [64dh][64key'], swizzled
#pragma unroll
        for (int i = 0; i < 2; ++i) {
            int e = (i * 256 + tid) * 8;
            int r = e >> 6, c = e & 63;
            int cs = c ^ (((r ^ (r >> 3)) & 7) << 3);
            *(u32x4*)&Kl[r][cs] = *(const u32x4*)(K + (rowbase + kb + r) * 1024 + hoff + c);
            *(u32x4*)&Vl[r][cs] = *(const u32x4*)(Vt_g + vbase + (size_t)r * 2048 + kb + c);
        }
        if (tid < 64) mlf[tid] = (mask[rowbase + kb + tid] == 0) ? -30000.0f : 0.0f;
        __syncthreads();

        // S^T = K x Q^T : st[t] holds C[key][q] for keys [32t, 32t+32)
        f32x16 st[2];
#pragma unroll
        for (int t = 0; t < 2; ++t) {
            const int swt = t ? sw1 : sw0;
            f32x16 z = {};
#pragma unroll
            for (int kk = 0; kk < 4; ++kk) {
                bf16x8 kf = ldfrag(&Kl[t * 32 + l31][(kk * 16 + hi * 8) ^ swt]);
                z = __builtin_amdgcn_mfma_f32_32x32x16_bf16(kf, aq[kk], z, 0, 0, 0);
            }
            st[t] = z;
        }

        // p = exp2(s + maskf); per-lane partial denominator; pack per 4-key group
        unsigned int pk[2][4][2];
#pragma unroll
        for (int t = 0; t < 2; ++t)
#pragma unroll
            for (int g = 0; g < 4; ++g) {
                f32x4 mf = *(const f32x4*)&mlf[t * 32 + g * 8 + hi * 4];
                float p0 = __builtin_amdgcn_exp2f(st[t][g * 4 + 0] + mf[0]);
                float p1 = __builtin_amdgcn_exp2f(st[t][g * 4 + 1] + mf[1]);
                float p2 = __builtin_amdgcn_exp2f(st[t][g * 4 + 2] + mf[2]);
                float p3 = __builtin_amdgcn_exp2f(st[t][g * 4 + 3] + mf[3]);
                lsum += (p0 + p1) + (p2 + p3);
                pk[t][g][0] = pack2(p0, p1);
                pk[t][g][1] = pack2(p2, p3);
            }

        // O += P * V over 4 k-chunks of 16 keys. Chunk c=(t,G): A-frag slot
        // (hi,j<4) = key 32t+8G+4hi+j (own pk[t][G]), (hi,j>=4) = key
        // 32t+8(G+1)+4hi+(j-4) (own pk[t][G+1]). V stored bit-2/3-permuted so
        // a straight b128 read at position 16c+8hi supplies matching keys.
#pragma unroll
        for (int c = 0; c < 4; ++c) {
            const int t = c >> 1, G = (c & 1) * 2;
            u32x4 fu = {pk[t][G][0], pk[t][G][1], pk[t][G + 1][0], pk[t][G + 1][1]};
            bf16x8 pf = __builtin_bit_cast(bf16x8, fu);
#pragma unroll
            for (int dt = 0; dt < 2; ++dt) {
                const int swd = dt ? sw1 : sw0;
                bf16x8 vb = ldfrag(&Vl[dt * 32 + l31][(c * 16 + hi * 8) ^ swd]);
                o[dt] = __builtin_amdgcn_mfma_f32_32x32x16_bf16(pf, vb, o[dt], 0, 0, 0);
            }
        }
        __syncthreads();
    }

    // denominator: lane covers keys ≡ {4hi..4hi+3} mod 8 for q=l31; partner
    // lane (^32) has the rest
    lsum += __shfl_xor(lsum, 32);
    if (lane < 32) lsq[w * 32 + lane] = 1.0f / lsum;
    __syncthreads();

#pragma unroll
    for (int g = 0; g < 4; ++g) {
        f32x4 inv = *(const f32x4*)&lsq[w * 32 + g * 8 + hi * 4];
#pragma unroll
        for (int j = 0; j < 4; ++j) {
            const size_t row = rowbase + q0 + w * 32 + g * 8 + hi * 4 + j;
#pragma unroll
            for (int dt = 0; dt < 2; ++dt)
                O[row * 1024 + hoff + dt * 32 + l31] = f2bf(o[dt][g * 4 + j] * inv[j]);
        }
    }
}

// In-place LayerNorm over last dim (1024), one row per block.
__global__ __launch_bounds__(256) void ln_inplace(
    float* __restrict__ X, const float* __restrict__ gamma, const float* __restrict__ beta)
{
    __shared__ float red[8];
    const int tid = threadIdx.x, lane = tid & 63, w = tid >> 6;
    float* p = X + (size_t)blockIdx.x * 1024;
    f32x4 v = *((const f32x4*)p + tid);
    float s = v[0] + v[1] + v[2] + v[3];
    float s2 = v[0] * v[0] + v[1] * v[1] + v[2] * v[2] + v[3] * v[3];
#pragma unroll
    for (int d = 1; d < 64; d <<= 1) {
        s += __shfl_xor(s, d);
        s2 += __shfl_xor(s2, d);
    }
    if (lane == 0) { red[w] = s; red[4 + w] = s2; }
    __syncthreads();
    s = red[0] + red[1] + red[2] + red[3];
    s2 = red[4] + red[5] + red[6] + red[7];
    const float mu = s * (1.0f / 1024.0f);
    const float var = s2 * (1.0f / 1024.0f) - mu * mu;
    const float rstd = rsqrtf(var + 1e-5f);
    f32x4 g = *((const f32x4*)gamma + tid);
    f32x4 be = *((const f32x4*)beta + tid);
    f32x4 out;
#pragma unroll
    for (int j = 0; j < 4; ++j) out[j] = (v[j] - mu) * rstd * g[j] + be[j];
    *((f32x4*)p + tid) = out;
}

extern "C" void kernel_launch(void* const* d_in, const int* in_sizes, int n_in,
                              void* d_out, int out_size, void* d_ws, size_t ws_size,
                              hipStream_t stream) {
    const float* query = (const float*)d_in[0];
    const float* key_  = (const float*)d_in[1];
    const float* value = (const float*)d_in[2];
    const int*   mask  = (const int*)d_in[3];
    const float* Wq = (const float*)d_in[4];
    const float* bq = (const float*)d_in[5];
    const float* Wk = (const float*)d_in[6];
    const float* bk = (const float*)d_in[7];
    const float* Wv = (const float*)d_in[8];
    const float* bv = (const float*)d_in[9];
    const float* Wo = (const float*)d_in[10];
    const float* bo = (const float*)d_in[11];
    const float* gamma = (const float*)d_in[12];
    const float* beta  = (const float*)d_in[13];

    const size_t MD = (size_t)8192 * 1024;
    unsigned short* Qb  = (unsigned short*)d_ws;
    unsigned short* Kb  = Qb + MD;
    unsigned short* Vtb = Kb + MD;   // permuted V^T: [b*16+h][dh][key bits2/3 swapped]
    unsigned short* Ab  = Vtb + MD;
    float* out = (float*)d_out;

    dim3 gg(64, 8);
    // Q scaled by log2(e)/sqrt(DH) so QK^T lands in exp2 domain
    const float qscale = 0.125f * 1.4426950408889634f;
    gemm_bt<true, 0><<<gg, 256, 0, stream>>>(query, Wq, bq, nullptr, Qb, qscale);
    gemm_bt<true, 0><<<gg, 256, 0, stream>>>(key_, Wk, bk, nullptr, Kb, 1.0f);
    gemm_bt<true, 2><<<gg, 256, 0, stream>>>(value, Wv, bv, nullptr, Vtb, 1.0f);
    attn_fwd<<<dim3(16, 64), 256, 0, stream>>>(Qb, Kb, Vtb, mask, Ab);
    gemm_bt<false, 1><<<gg, 256, 0, stream>>>(Ab, Wo, bo, query, out, 1.0f);
    ln_inplace<<<8192, 256, 0, stream>>>(out, gamma, beta);
}

// Round 6
// 300.734 us; speedup vs baseline: 1.1464x; 1.1464x over previous
//
#include <hip/hip_runtime.h>
#include <hip/hip_bf16.h>

typedef __attribute__((ext_vector_type(4))) float f32x4;
typedef __attribute__((ext_vector_type(16))) float f32x16;
typedef __attribute__((ext_vector_type(2))) unsigned int u32x2;
typedef __attribute__((ext_vector_type(4))) unsigned int u32x4;
typedef __attribute__((ext_vector_type(8))) __bf16 bf16x8;

// fp32 -> bf16 via HW cvt (RTNE)
__device__ inline unsigned short f2bf(float x) {
    return __builtin_bit_cast(unsigned short, (__bf16)x);
}
__device__ inline unsigned int pack2(float lo, float hi) {
    return (unsigned int)f2bf(lo) | ((unsigned int)f2bf(hi) << 16);
}
// load 8 fp32, convert to 8 packed bf16 (16B)
__device__ inline u32x4 cvt8(const float* __restrict__ p) {
    f32x4 a = *(const f32x4*)p;
    f32x4 b = *(const f32x4*)(p + 4);
    u32x4 r;
    r[0] = pack2(a[0], a[1]);
    r[1] = pack2(a[2], a[3]);
    r[2] = pack2(b[0], b[1]);
    r[3] = pack2(b[2], b[3]);
    return r;
}
__device__ inline bf16x8 ldfrag(const unsigned short* p) {
    u32x4 t = *(const u32x4*)p;
    return __builtin_bit_cast(bf16x8, t);
}

// C[M=8192][N=1024] = A[8192][1024] * B[1024][1024]^T, epilogue variants.
// AF32: A is fp32 (convert during staging), else bf16 (ushort).
// MODE 0: bf16 output (acc+bias)*alpha, row-major [token][d]
// MODE 1: fp32 output acc+bias+resid (output projection)
// MODE 2: bf16 output acc+bias, transposed per-head [b*16+h][dh][key'],
//         with key' = key with bits 2<->3 swapped (pre-permuted for attn PV
//         fragment order; the swap maps aligned 4-key runs to aligned runs).
template<bool AF32, int MODE>
__global__ __launch_bounds__(256) void gemm_bt(
    const void* __restrict__ Ap, const float* __restrict__ Bw,
    const float* __restrict__ bias, const float* __restrict__ resid,
    void* __restrict__ Cp, float alpha)
{
    __shared__ unsigned short Al[128][40];   // pad 32->40 (80B stride: 2-way = free)
    __shared__ unsigned short Bl[128][40];
    const int tid = threadIdx.x;
    const int lane = tid & 63, w = tid >> 6;
    const int wr = w >> 1, wc = w & 1;
    const int m0 = blockIdx.x * 128, n0 = blockIdx.y * 128;
    const int fr = lane & 15, fq = lane >> 4;

    f32x4 acc[4][4] = {};

    for (int k0 = 0; k0 < 1024; k0 += 32) {
#pragma unroll
        for (int i = 0; i < 2; ++i) {
            int e = (i * 256 + tid) * 8;
            int r = e >> 5, c = e & 31;
            u32x4 av;
            if (AF32) av = cvt8((const float*)Ap + (size_t)(m0 + r) * 1024 + k0 + c);
            else {
                u32x4 t = *(const u32x4*)((const unsigned short*)Ap + (size_t)(m0 + r) * 1024 + k0 + c);
                av = t;
            }
            *(u32x4*)&Al[r][c] = av;
            u32x4 bv = cvt8(Bw + (size_t)(n0 + r) * 1024 + k0 + c);
            *(u32x4*)&Bl[r][c] = bv;
        }
        __syncthreads();
        bf16x8 af[4], bfv[4];
#pragma unroll
        for (int mt = 0; mt < 4; ++mt)
            af[mt] = ldfrag(&Al[wr * 64 + mt * 16 + fr][8 * fq]);
#pragma unroll
        for (int nt = 0; nt < 4; ++nt)
            bfv[nt] = ldfrag(&Bl[wc * 64 + nt * 16 + fr][8 * fq]);
#pragma unroll
        for (int mt = 0; mt < 4; ++mt)
#pragma unroll
            for (int nt = 0; nt < 4; ++nt)
                acc[mt][nt] = __builtin_amdgcn_mfma_f32_16x16x32_bf16(af[mt], bfv[nt], acc[mt][nt], 0, 0, 0);
        __syncthreads();
    }

#pragma unroll
    for (int mt = 0; mt < 4; ++mt) {
#pragma unroll
        for (int nt = 0; nt < 4; ++nt) {
            const int col = n0 + wc * 64 + nt * 16 + fr;
            const float bb = bias[col];
            const int row0 = m0 + wr * 64 + mt * 16 + fq * 4;
            if (MODE == 2) {
                // V^T with key bits 2<->3 swapped: 4 consecutive keys -> 8B
                float v0 = acc[mt][nt][0] + bb, v1 = acc[mt][nt][1] + bb;
                float v2 = acc[mt][nt][2] + bb, v3 = acc[mt][nt][3] + bb;
                const int bb_ = row0 >> 11, key = row0 & 2047;
                const int key2 = (key & ~12) | ((key & 4) << 1) | ((key & 8) >> 1);
                const size_t idx = ((size_t)bb_ * 1024 + col) * 2048 + key2;
                u32x2 pv;
                pv[0] = pack2(v0, v1);
                pv[1] = pack2(v2, v3);
                *(u32x2*)((unsigned short*)Cp + idx) = pv;
            } else {
#pragma unroll
                for (int r = 0; r < 4; ++r) {
                    const size_t idx = (size_t)(row0 + r) * 1024 + col;
                    float v = (acc[mt][nt][r] + bb) * alpha;
                    if (MODE == 1) ((float*)Cp)[idx] = v + resid[idx];
                    else           ((unsigned short*)Cp)[idx] = f2bf(v);
                }
            }
        }
    }
}

// Flash attention, 32x32 MFMA, swapped QK^T, softmax fully in registers.
// Round-6 schedule: 2 waves/block (QBLK=64 -> 2048 blocks), KVBLK=64,
// T14 async staging (issue next tile's global loads before compute; ds_write
// after the loop-top barrier), s_setprio(1) around MFMA clusters.
// QK^T: mfma(A=K, B=Q) -> C[key][q]: q = lane&31, key = (r&3)+8*(r>>2)+4*hi.
// PV A-fragment = lane's own packed P words (V stored key-bit-2/3-permuted).
__global__ __launch_bounds__(128) void attn_fwd(
    const unsigned short* __restrict__ Q, const unsigned short* __restrict__ K,
    const unsigned short* __restrict__ Vt_g, const int* __restrict__ mask,
    unsigned short* __restrict__ O)
{
    __shared__ unsigned short Kl[64][64];   // [key][dh], XOR-swizzled
    __shared__ unsigned short Vl[64][64];   // [dh][key'], XOR-swizzled
    __shared__ float mlf[64];
    __shared__ float lsq[64];               // per-q reciprocal denominators
    const int tid = threadIdx.x, lane = tid & 63, w = tid >> 6;  // w in {0,1}
    const int l31 = lane & 31, hi = lane >> 5;
    const int q0 = blockIdx.x * 64;
    const int b = blockIdx.y >> 4;
    const size_t rowbase = (size_t)b * 2048;
    const int hoff = (blockIdx.y & 15) * 64;
    const size_t vbase = (size_t)blockIdx.y * 64 * 2048;

    // swizzle keys for fragment-read rows r = t*32 + l31 (t = 0,1)
    const int sw0 = (((l31) ^ (l31 >> 3)) & 7) << 3;
    const int sw1 = (((l31) ^ ((l31 >> 3) + 4)) & 7) << 3;

    // Q fragments (B-operand): lane holds Q[q0+w*32+l31][kk*16 + hi*8 + j]
    bf16x8 aq[4];
    {
        const unsigned short* qp = Q + (rowbase + q0 + w * 32 + l31) * 1024 + hoff + hi * 8;
#pragma unroll
        for (int kk = 0; kk < 4; ++kk) aq[kk] = ldfrag(qp + kk * 16);
    }
    f32x16 o[2] = {};
    float lsum = 0.f;

    // staging geometry: 128 threads x 4 chunks of 16B cover one 64x64 tile
    int srow[4], scol[4];
#pragma unroll
    for (int i = 0; i < 4; ++i) {
        int e = (i * 128 + tid) * 8;
        srow[i] = e >> 6;
        scol[i] = e & 63;
    }

    // T14 prologue: issue tile-0 loads into regs
    u32x4 kpre[4], vpre[4];
    int mpre = 0;
#pragma unroll
    for (int i = 0; i < 4; ++i) {
        kpre[i] = *(const u32x4*)(K + (rowbase + srow[i]) * 1024 + hoff + scol[i]);
        vpre[i] = *(const u32x4*)(Vt_g + vbase + (size_t)srow[i] * 2048 + scol[i]);
    }
    if (hi == 0) mpre = mask[rowbase + w * 32 + l31];

    for (int kb = 0; kb < 2048; kb += 64) {
        __syncthreads();   // all waves finished reading previous tile
#pragma unroll
        for (int i = 0; i < 4; ++i) {
            const int cs = scol[i] ^ (((srow[i] ^ (srow[i] >> 3)) & 7) << 3);
            *(u32x4*)&Kl[srow[i]][cs] = kpre[i];
            *(u32x4*)&Vl[srow[i]][cs] = vpre[i];
        }
        if (hi == 0) mlf[w * 32 + l31] = (mpre == 0) ? -30000.0f : 0.0f;
        __syncthreads();   // tile ready

        // T14: issue next tile's loads now; they fly during this compute
        if (kb + 64 < 2048) {
#pragma unroll
            for (int i = 0; i < 4; ++i) {
                kpre[i] = *(const u32x4*)(K + (rowbase + kb + 64 + srow[i]) * 1024 + hoff + scol[i]);
                vpre[i] = *(const u32x4*)(Vt_g + vbase + (size_t)srow[i] * 2048 + kb + 64 + scol[i]);
            }
            if (hi == 0) mpre = mask[rowbase + kb + 64 + w * 32 + l31];
        }

        // per-32-key subtile: QK^T -> softmax -> PV (interleaves MFMA & VALU)
#pragma unroll
        for (int t = 0; t < 2; ++t) {
            const int swt = t ? sw1 : sw0;
            f32x16 z = {};
            __builtin_amdgcn_s_setprio(1);
#pragma unroll
            for (int kk = 0; kk < 4; ++kk) {
                bf16x8 kf = ldfrag(&Kl[t * 32 + l31][(kk * 16 + hi * 8) ^ swt]);
                z = __builtin_amdgcn_mfma_f32_32x32x16_bf16(kf, aq[kk], z, 0, 0, 0);
            }
            __builtin_amdgcn_s_setprio(0);

            unsigned int pk[4][2];
#pragma unroll
            for (int g = 0; g < 4; ++g) {
                f32x4 mf = *(const f32x4*)&mlf[t * 32 + g * 8 + hi * 4];
                float p0 = __builtin_amdgcn_exp2f(z[g * 4 + 0] + mf[0]);
                float p1 = __builtin_amdgcn_exp2f(z[g * 4 + 1] + mf[1]);
                float p2 = __builtin_amdgcn_exp2f(z[g * 4 + 2] + mf[2]);
                float p3 = __builtin_amdgcn_exp2f(z[g * 4 + 3] + mf[3]);
                lsum += (p0 + p1) + (p2 + p3);
                pk[g][0] = pack2(p0, p1);
                pk[g][1] = pack2(p2, p3);
            }

            // PV over the two 16-key chunks of this subtile (c = 2t + half).
            // A-frag slot (hi, j<4) = key 32t+8G+4hi+j  (own pk[G]),
            //            (hi, j>=4) = key 32t+8(G+1)+4hi+(j-4) (own pk[G+1]);
            // V stored key-bit-2/3-permuted so a straight b128 read matches.
#pragma unroll
            for (int half = 0; half < 2; ++half) {
                const int c = t * 2 + half, G = half * 2;
                u32x4 fu = {pk[G][0], pk[G][1], pk[G + 1][0], pk[G + 1][1]};
                bf16x8 pf = __builtin_bit_cast(bf16x8, fu);
                __builtin_amdgcn_s_setprio(1);
#pragma unroll
                for (int dt = 0; dt < 2; ++dt) {
                    const int swd = dt ? sw1 : sw0;
                    bf16x8 vb = ldfrag(&Vl[dt * 32 + l31][(c * 16 + hi * 8) ^ swd]);
                    o[dt] = __builtin_amdgcn_mfma_f32_32x32x16_bf16(pf, vb, o[dt], 0, 0, 0);
                }
                __builtin_amdgcn_s_setprio(0);
            }
        }
    }

    // denominator: lane covers keys ≡ {4hi..4hi+3} mod 8 for q=l31; partner
    // lane (^32) has the rest
    lsum += __shfl_xor(lsum, 32);
    if (lane < 32) lsq[w * 32 + lane] = 1.0f / lsum;
    __syncthreads();

#pragma unroll
    for (int g = 0; g < 4; ++g) {
        f32x4 inv = *(const f32x4*)&lsq[w * 32 + g * 8 + hi * 4];
#pragma unroll
        for (int j = 0; j < 4; ++j) {
            const size_t row = rowbase + q0 + w * 32 + g * 8 + hi * 4 + j;
#pragma unroll
            for (int dt = 0; dt < 2; ++dt)
                O[row * 1024 + hoff + dt * 32 + l31] = f2bf(o[dt][g * 4 + j] * inv[j]);
        }
    }
}

// In-place LayerNorm over last dim (1024), one row per block.
__global__ __launch_bounds__(256) void ln_inplace(
    float* __restrict__ X, const float* __restrict__ gamma, const float* __restrict__ beta)
{
    __shared__ float red[8];
    const int tid = threadIdx.x, lane = tid & 63, w = tid >> 6;
    float* p = X + (size_t)blockIdx.x * 1024;
    f32x4 v = *((const f32x4*)p + tid);
    float s = v[0] + v[1] + v[2] + v[3];
    float s2 = v[0] * v[0] + v[1] * v[1] + v[2] * v[2] + v[3] * v[3];
#pragma unroll
    for (int d = 1; d < 64; d <<= 1) {
        s += __shfl_xor(s, d);
        s2 += __shfl_xor(s2, d);
    }
    if (lane == 0) { red[w] = s; red[4 + w] = s2; }
    __syncthreads();
    s = red[0] + red[1] + red[2] + red[3];
    s2 = red[4] + red[5] + red[6] + red[7];
    const float mu = s * (1.0f / 1024.0f);
    const float var = s2 * (1.0f / 1024.0f) - mu * mu;
    const float rstd = rsqrtf(var + 1e-5f);
    f32x4 g = *((const f32x4*)gamma + tid);
    f32x4 be = *((const f32x4*)beta + tid);
    f32x4 out;
#pragma unroll
    for (int j = 0; j < 4; ++j) out[j] = (v[j] - mu) * rstd * g[j] + be[j];
    *((f32x4*)p + tid) = out;
}

extern "C" void kernel_launch(void* const* d_in, const int* in_sizes, int n_in,
                              void* d_out, int out_size, void* d_ws, size_t ws_size,
                              hipStream_t stream) {
    const float* query = (const float*)d_in[0];
    const float* key_  = (const float*)d_in[1];
    const float* value = (const float*)d_in[2];
    const int*   mask  = (const int*)d_in[3];
    const float* Wq = (const float*)d_in[4];
    const float* bq = (const float*)d_in[5];
    const float* Wk = (const float*)d_in[6];
    const float* bk = (const float*)d_in[7];
    const float* Wv = (const float*)d_in[8];
    const float* bv = (const float*)d_in[9];
    const float* Wo = (const float*)d_in[10];
    const float* bo = (const float*)d_in[11];
    const float* gamma = (const float*)d_in[12];
    const float* beta  = (const float*)d_in[13];

    const size_t MD = (size_t)8192 * 1024;
    unsigned short* Qb  = (unsigned short*)d_ws;
    unsigned short* Kb  = Qb + MD;
    unsigned short* Vtb = Kb + MD;   // permuted V^T: [b*16+h][dh][key bits2/3 swapped]
    unsigned short* Ab  = Vtb + MD;
    float* out = (float*)d_out;

    dim3 gg(64, 8);
    // Q scaled by log2(e)/sqrt(DH) so QK^T lands in exp2 domain
    const float qscale = 0.125f * 1.4426950408889634f;
    gemm_bt<true, 0><<<gg, 256, 0, stream>>>(query, Wq, bq, nullptr, Qb, qscale);
    gemm_bt<true, 0><<<gg, 256, 0, stream>>>(key_, Wk, bk, nullptr, Kb, 1.0f);
    gemm_bt<true, 2><<<gg, 256, 0, stream>>>(value, Wv, bv, nullptr, Vtb, 1.0f);
    attn_fwd<<<dim3(32, 64), 128, 0, stream>>>(Qb, Kb, Vtb, mask, Ab);
    gemm_bt<false, 1><<<gg, 256, 0, stream>>>(Ab, Wo, bo, query, out, 1.0f);
    ln_inplace<<<8192, 256, 0, stream>>>(out, gamma, beta);
}

// Round 7
// 246.956 us; speedup vs baseline: 1.3961x; 1.2178x over previous
//
#include <hip/hip_runtime.h>
#include <hip/hip_bf16.h>

typedef __attribute__((ext_vector_type(4))) float f32x4;
typedef __attribute__((ext_vector_type(16))) float f32x16;
typedef __attribute__((ext_vector_type(2))) unsigned int u32x2;
typedef __attribute__((ext_vector_type(4))) unsigned int u32x4;
typedef __attribute__((ext_vector_type(8))) __bf16 bf16x8;

// fp32 -> bf16 via HW cvt (RTNE)
__device__ inline unsigned short f2bf(float x) {
    return __builtin_bit_cast(unsigned short, (__bf16)x);
}
__device__ inline unsigned int pack2(float lo, float hi) {
    return (unsigned int)f2bf(lo) | ((unsigned int)f2bf(hi) << 16);
}
// load 8 fp32, convert to 8 packed bf16 (16B)
__device__ inline u32x4 cvt8(const float* __restrict__ p) {
    f32x4 a = *(const f32x4*)p;
    f32x4 b = *(const f32x4*)(p + 4);
    u32x4 r;
    r[0] = pack2(a[0], a[1]);
    r[1] = pack2(a[2], a[3]);
    r[2] = pack2(b[0], b[1]);
    r[3] = pack2(b[2], b[3]);
    return r;
}
__device__ inline bf16x8 ldfrag(const unsigned short* p) {
    u32x4 t = *(const u32x4*)p;
    return __builtin_bit_cast(bf16x8, t);
}

// ---------------- fp32 -> bf16 conversion kernels ----------------
__global__ __launch_bounds__(256) void cvt_bf16(
    const float* __restrict__ src, unsigned short* __restrict__ dst, int n8)
{
    for (int i = blockIdx.x * 256 + threadIdx.x; i < n8; i += gridDim.x * 256)
        *(u32x4*)(dst + (size_t)i * 8) = cvt8(src + (size_t)i * 8);
}
// 3 weight matrices (1024x1024 each) in one launch; grid (512, 3)
__global__ __launch_bounds__(256) void cvt_w3(
    const float* __restrict__ wq, const float* __restrict__ wk,
    const float* __restrict__ wv, unsigned short* __restrict__ dst)
{
    const float* s = blockIdx.y == 0 ? wq : (blockIdx.y == 1 ? wk : wv);
    unsigned short* d = dst + (size_t)blockIdx.y * 1048576;
    const int i = blockIdx.x * 256 + threadIdx.x;
    *(u32x4*)(d + (size_t)i * 8) = cvt8(s + (size_t)i * 8);
}

// ---------------- GEMM: C[8192][1024] = A * B^T (both bf16) ----------------
// m97 structure: linear LDS tiles staged via global_load_lds (16B), 2-phase.
// MODE 0: bf16 output (acc+bias)*alpha, row-major [token][d]
// MODE 1: fp32 output acc+bias+resid (output projection)
// MODE 2: bf16 output acc+bias, transposed per-head [b*16+h][dh][key'],
//         key' = key with bits 2<->3 swapped (pre-permuted for attn PV).
template<int MODE>
__global__ __launch_bounds__(256) void gemm_bt(
    const unsigned short* __restrict__ A, const unsigned short* __restrict__ Bw,
    const float* __restrict__ bias, const float* __restrict__ resid,
    void* __restrict__ Cp, float alpha)
{
    __shared__ unsigned short Al[128][32];   // linear (global_load_lds dest)
    __shared__ unsigned short Bl[128][32];
    const int tid = threadIdx.x;
    const int lane = tid & 63, w = tid >> 6;
    const int wr = w >> 1, wc = w & 1;
    const int m0 = blockIdx.x * 128, n0 = blockIdx.y * 128;
    const int fr = lane & 15, fq = lane >> 4;

    f32x4 acc[4][4] = {};

    for (int k0 = 0; k0 < 1024; k0 += 32) {
        // stage 128x32 tiles: 4 waves x 2 rounds x (64 lanes x 16B) each
#pragma unroll
        for (int j = 0; j < 2; ++j) {
            const int f = (w * 2 + j) * 512 + lane * 8;   // halfword index
            const int r = f >> 5, c = f & 31;
            __builtin_amdgcn_global_load_lds(
                (const __attribute__((address_space(1))) void*)(A + (size_t)(m0 + r) * 1024 + k0 + c),
                (__attribute__((address_space(3))) void*)(&Al[0][0] + (w * 2 + j) * 512),
                16, 0, 0);
            __builtin_amdgcn_global_load_lds(
                (const __attribute__((address_space(1))) void*)(Bw + (size_t)(n0 + r) * 1024 + k0 + c),
                (__attribute__((address_space(3))) void*)(&Bl[0][0] + (w * 2 + j) * 512),
                16, 0, 0);
        }
        __syncthreads();
        bf16x8 af[4], bfv[4];
#pragma unroll
        for (int mt = 0; mt < 4; ++mt)
            af[mt] = ldfrag(&Al[wr * 64 + mt * 16 + fr][8 * fq]);
#pragma unroll
        for (int nt = 0; nt < 4; ++nt)
            bfv[nt] = ldfrag(&Bl[wc * 64 + nt * 16 + fr][8 * fq]);
#pragma unroll
        for (int mt = 0; mt < 4; ++mt)
#pragma unroll
            for (int nt = 0; nt < 4; ++nt)
                acc[mt][nt] = __builtin_amdgcn_mfma_f32_16x16x32_bf16(af[mt], bfv[nt], acc[mt][nt], 0, 0, 0);
        __syncthreads();
    }

#pragma unroll
    for (int mt = 0; mt < 4; ++mt) {
#pragma unroll
        for (int nt = 0; nt < 4; ++nt) {
            const int col = n0 + wc * 64 + nt * 16 + fr;
            const float bb = bias[col];
            const int row0 = m0 + wr * 64 + mt * 16 + fq * 4;
            if (MODE == 2) {
                float v0 = acc[mt][nt][0] + bb, v1 = acc[mt][nt][1] + bb;
                float v2 = acc[mt][nt][2] + bb, v3 = acc[mt][nt][3] + bb;
                const int bb_ = row0 >> 11, key = row0 & 2047;
                const int key2 = (key & ~12) | ((key & 4) << 1) | ((key & 8) >> 1);
                const size_t idx = ((size_t)bb_ * 1024 + col) * 2048 + key2;
                u32x2 pv;
                pv[0] = pack2(v0, v1);
                pv[1] = pack2(v2, v3);
                *(u32x2*)((unsigned short*)Cp + idx) = pv;
            } else {
#pragma unroll
                for (int r = 0; r < 4; ++r) {
                    const size_t idx = (size_t)(row0 + r) * 1024 + col;
                    float v = (acc[mt][nt][r] + bb) * alpha;
                    if (MODE == 1) ((float*)Cp)[idx] = v + resid[idx];
                    else           ((unsigned short*)Cp)[idx] = f2bf(v);
                }
            }
        }
    }
}

// ---------------- Flash attention ----------------
// 4 waves x 64 q-rows/wave (2 q-groups of 32) = 256 q-rows per block.
// KVBLK=64, ping-pong double-buffered K/V in LDS, ONE barrier per tile.
// Q pre-scaled by log2(e)/sqrt(DH); mask additive in log2 domain; no max
// tracking (scores bounded); denominator deferred to kernel end.
// QK^T: mfma(A=K, B=Q) -> C[key][q]: q = lane&31, key = (r&3)+8*(r>>2)+4*hi.
// PV A-fragment = lane's own packed P words (V stored key-bit-2/3-permuted).
__global__ __launch_bounds__(256, 2) void attn_fwd(
    const unsigned short* __restrict__ Q, const unsigned short* __restrict__ K,
    const unsigned short* __restrict__ Vt_g, const int* __restrict__ mask,
    unsigned short* __restrict__ O)
{
    __shared__ unsigned short Kl[2][64][64];   // [buf][key][dh], XOR-swizzled
    __shared__ unsigned short Vl[2][64][64];   // [buf][dh][key'], XOR-swizzled
    __shared__ float mlf[2][64];
    __shared__ float lsq[256];
    const int tid = threadIdx.x, lane = tid & 63, w = tid >> 6;  // w in 0..3
    const int l31 = lane & 31, hi = lane >> 5;
    const int q0 = blockIdx.x * 256;
    const int b = blockIdx.y >> 4;
    const size_t rowbase = (size_t)b * 2048;
    const int hoff = (blockIdx.y & 15) * 64;
    const size_t vbase = (size_t)blockIdx.y * 64 * 2048;

    // swizzle keys for fragment-read rows r = t*32 + l31 (t = 0,1)
    const int sw0 = (((l31) ^ (l31 >> 3)) & 7) << 3;
    const int sw1 = (((l31) ^ ((l31 >> 3) + 4)) & 7) << 3;

    // Q fragments: group a covers q-row q0 + w*64 + a*32 + l31
    bf16x8 aq[2][4];
#pragma unroll
    for (int a = 0; a < 2; ++a) {
        const unsigned short* qp = Q + (rowbase + q0 + w * 64 + a * 32 + l31) * 1024 + hoff + hi * 8;
#pragma unroll
        for (int kk = 0; kk < 4; ++kk) aq[a][kk] = ldfrag(qp + kk * 16);
    }
    f32x16 o[2][2] = {};
    float lsum[2] = {0.f, 0.f};

    // staging: 256 threads x 2 chunks of 16B cover one 64x64 bf16 tile
    int srow[2], scol[2];
#pragma unroll
    for (int i = 0; i < 2; ++i) {
        int e = (i * 256 + tid) * 8;
        srow[i] = e >> 6;
        scol[i] = e & 63;
    }

    // prologue: tile 0 into regs
    u32x4 kpre[2], vpre[2];
    int mpre = 0;
#pragma unroll
    for (int i = 0; i < 2; ++i) {
        kpre[i] = *(const u32x4*)(K + (rowbase + srow[i]) * 1024 + hoff + scol[i]);
        vpre[i] = *(const u32x4*)(Vt_g + vbase + (size_t)srow[i] * 2048 + scol[i]);
    }
    if (tid < 64) mpre = mask[rowbase + tid];

    for (int kb = 0, it = 0; kb < 2048; kb += 64, ++it) {
        const int p = it & 1;
        // write tile `it` from regs into buf p (reads of buf p at iter it-2
        // are separated from this write by the iter it-1 barrier)
#pragma unroll
        for (int i = 0; i < 2; ++i) {
            const int cs = scol[i] ^ (((srow[i] ^ (srow[i] >> 3)) & 7) << 3);
            *(u32x4*)&Kl[p][srow[i]][cs] = kpre[i];
            *(u32x4*)&Vl[p][srow[i]][cs] = vpre[i];
        }
        if (tid < 64) mlf[p][tid] = (mpre == 0) ? -30000.0f : 0.0f;
        // T14: issue next tile's global loads; they fly during barrier+compute
        if (kb + 64 < 2048) {
#pragma unroll
            for (int i = 0; i < 2; ++i) {
                kpre[i] = *(const u32x4*)(K + (rowbase + kb + 64 + srow[i]) * 1024 + hoff + scol[i]);
                vpre[i] = *(const u32x4*)(Vt_g + vbase + (size_t)srow[i] * 2048 + kb + 64 + scol[i]);
            }
            if (tid < 64) mpre = mask[rowbase + kb + 64 + tid];
        }
        __syncthreads();   // buf p ready (single barrier per tile)

#pragma unroll
        for (int t = 0; t < 2; ++t) {
            const int swt = t ? sw1 : sw0;
            // QK^T for both q-groups, K-fragments register-reused
            f32x16 z0 = {}, z1 = {};
            __builtin_amdgcn_s_setprio(1);
#pragma unroll
            for (int kk = 0; kk < 4; ++kk) {
                bf16x8 kf = ldfrag(&Kl[p][t * 32 + l31][(kk * 16 + hi * 8) ^ swt]);
                z0 = __builtin_amdgcn_mfma_f32_32x32x16_bf16(kf, aq[0][kk], z0, 0, 0, 0);
                z1 = __builtin_amdgcn_mfma_f32_32x32x16_bf16(kf, aq[1][kk], z1, 0, 0, 0);
            }
            __builtin_amdgcn_s_setprio(0);

            // softmax (exp2 domain) for both groups; pack per 4-key group
            unsigned int pk[2][4][2];
#pragma unroll
            for (int g = 0; g < 4; ++g) {
                f32x4 mf = *(const f32x4*)&mlf[p][t * 32 + g * 8 + hi * 4];
                {
                    float p0 = __builtin_amdgcn_exp2f(z0[g * 4 + 0] + mf[0]);
                    float p1 = __builtin_amdgcn_exp2f(z0[g * 4 + 1] + mf[1]);
                    float p2 = __builtin_amdgcn_exp2f(z0[g * 4 + 2] + mf[2]);
                    float p3 = __builtin_amdgcn_exp2f(z0[g * 4 + 3] + mf[3]);
                    lsum[0] += (p0 + p1) + (p2 + p3);
                    pk[0][g][0] = pack2(p0, p1);
                    pk[0][g][1] = pack2(p2, p3);
                }
                {
                    float p0 = __builtin_amdgcn_exp2f(z1[g * 4 + 0] + mf[0]);
                    float p1 = __builtin_amdgcn_exp2f(z1[g * 4 + 1] + mf[1]);
                    float p2 = __builtin_amdgcn_exp2f(z1[g * 4 + 2] + mf[2]);
                    float p3 = __builtin_amdgcn_exp2f(z1[g * 4 + 3] + mf[3]);
                    lsum[1] += (p0 + p1) + (p2 + p3);
                    pk[1][g][0] = pack2(p0, p1);
                    pk[1][g][1] = pack2(p2, p3);
                }
            }

            // PV: V-fragments register-reused across both q-groups
#pragma unroll
            for (int half = 0; half < 2; ++half) {
                const int c = t * 2 + half, G = half * 2;
                u32x4 fu0 = {pk[0][G][0], pk[0][G][1], pk[0][G + 1][0], pk[0][G + 1][1]};
                u32x4 fu1 = {pk[1][G][0], pk[1][G][1], pk[1][G + 1][0], pk[1][G + 1][1]};
                bf16x8 pf0 = __builtin_bit_cast(bf16x8, fu0);
                bf16x8 pf1 = __builtin_bit_cast(bf16x8, fu1);
                __builtin_amdgcn_s_setprio(1);
#pragma unroll
                for (int dt = 0; dt < 2; ++dt) {
                    const int swd = dt ? sw1 : sw0;
                    bf16x8 vb = ldfrag(&Vl[p][dt * 32 + l31][(c * 16 + hi * 8) ^ swd]);
                    o[0][dt] = __builtin_amdgcn_mfma_f32_32x32x16_bf16(pf0, vb, o[0][dt], 0, 0, 0);
                    o[1][dt] = __builtin_amdgcn_mfma_f32_32x32x16_bf16(pf1, vb, o[1][dt], 0, 0, 0);
                }
                __builtin_amdgcn_s_setprio(0);
            }
        }
    }

    // deferred denominator: partner lane (^32) holds the complementary keys
#pragma unroll
    for (int a = 0; a < 2; ++a) {
        lsum[a] += __shfl_xor(lsum[a], 32);
        if (lane < 32) lsq[w * 64 + a * 32 + lane] = 1.0f / lsum[a];
    }
    __syncthreads();

#pragma unroll
    for (int a = 0; a < 2; ++a)
#pragma unroll
        for (int g = 0; g < 4; ++g) {
            f32x4 inv = *(const f32x4*)&lsq[w * 64 + a * 32 + g * 8 + hi * 4];
#pragma unroll
            for (int j = 0; j < 4; ++j) {
                const size_t row = rowbase + q0 + w * 64 + a * 32 + g * 8 + hi * 4 + j;
#pragma unroll
                for (int dt = 0; dt < 2; ++dt)
                    O[row * 1024 + hoff + dt * 32 + l31] = f2bf(o[a][dt][g * 4 + j] * inv[j]);
            }
        }
}

// In-place LayerNorm over last dim (1024), one row per block.
__global__ __launch_bounds__(256) void ln_inplace(
    float* __restrict__ X, const float* __restrict__ gamma, const float* __restrict__ beta)
{
    __shared__ float red[8];
    const int tid = threadIdx.x, lane = tid & 63, w = tid >> 6;
    float* p = X + (size_t)blockIdx.x * 1024;
    f32x4 v = *((const f32x4*)p + tid);
    float s = v[0] + v[1] + v[2] + v[3];
    float s2 = v[0] * v[0] + v[1] * v[1] + v[2] * v[2] + v[3] * v[3];
#pragma unroll
    for (int d = 1; d < 64; d <<= 1) {
        s += __shfl_xor(s, d);
        s2 += __shfl_xor(s2, d);
    }
    if (lane == 0) { red[w] = s; red[4 + w] = s2; }
    __syncthreads();
    s = red[0] + red[1] + red[2] + red[3];
    s2 = red[4] + red[5] + red[6] + red[7];
    const float mu = s * (1.0f / 1024.0f);
    const float var = s2 * (1.0f / 1024.0f) - mu * mu;
    const float rstd = rsqrtf(var + 1e-5f);
    f32x4 g = *((const f32x4*)gamma + tid);
    f32x4 be = *((const f32x4*)beta + tid);
    f32x4 out;
#pragma unroll
    for (int j = 0; j < 4; ++j) out[j] = (v[j] - mu) * rstd * g[j] + be[j];
    *((f32x4*)p + tid) = out;
}

extern "C" void kernel_launch(void* const* d_in, const int* in_sizes, int n_in,
                              void* d_out, int out_size, void* d_ws, size_t ws_size,
                              hipStream_t stream) {
    const float* query = (const float*)d_in[0];
    const float* key_  = (const float*)d_in[1];
    const float* value = (const float*)d_in[2];
    const int*   mask  = (const int*)d_in[3];
    const float* Wq = (const float*)d_in[4];
    const float* bq = (const float*)d_in[5];
    const float* Wk = (const float*)d_in[6];
    const float* bk = (const float*)d_in[7];
    const float* Wv = (const float*)d_in[8];
    const float* bv = (const float*)d_in[9];
    const float* Wo = (const float*)d_in[10];
    const float* bo = (const float*)d_in[11];
    const float* gamma = (const float*)d_in[12];
    const float* beta  = (const float*)d_in[13];

    const size_t MD = (size_t)8192 * 1024;
    unsigned short* Qb  = (unsigned short*)d_ws;
    unsigned short* Kb  = Qb + MD;
    unsigned short* Vtb = Kb + MD;   // permuted V^T: [b*16+h][dh][key bits2/3 swapped]
    unsigned short* Ab  = Vtb + MD;  // (a) staging buf for bf16 inputs, (b) attn out
    float* out = (float*)d_out;
    // weights (bf16) live in d_out scratch until gemmO overwrites it
    unsigned short* W16 = (unsigned short*)d_out;     // Wq @0, Wk @1M, Wv @2M elems
    unsigned short* Wo16 = Vtb;                       // after attn, Vtb is free

    dim3 gg(64, 8);
    const float qscale = 0.125f * 1.4426950408889634f;  // 1/sqrt(64) * log2(e)

    // bf16 weights for QKV projections -> d_out scratch
    cvt_w3<<<dim3(512, 3), 256, 0, stream>>>(Wq, Wk, Wv, W16);
    // Q = query @ Wq^T  (input converted into Ab region, then consumed)
    cvt_bf16<<<2048, 256, 0, stream>>>(query, Ab, 1048576);
    gemm_bt<0><<<gg, 256, 0, stream>>>(Ab, W16, bq, nullptr, Qb, qscale);
    cvt_bf16<<<2048, 256, 0, stream>>>(key_, Ab, 1048576);
    gemm_bt<0><<<gg, 256, 0, stream>>>(Ab, W16 + 1048576, bk, nullptr, Kb, 1.0f);
    cvt_bf16<<<2048, 256, 0, stream>>>(value, Ab, 1048576);
    gemm_bt<2><<<gg, 256, 0, stream>>>(Ab, W16 + 2097152, bv, nullptr, Vtb, 1.0f);

    attn_fwd<<<dim3(8, 64), 256, 0, stream>>>(Qb, Kb, Vtb, mask, Ab);

    cvt_bf16<<<512, 256, 0, stream>>>(Wo, Wo16, 131072);
    gemm_bt<1><<<gg, 256, 0, stream>>>(Ab, Wo16, bo, query, out, 1.0f);
    ln_inplace<<<8192, 256, 0, stream>>>(out, gamma, beta);
}

// Round 8
// 238.928 us; speedup vs baseline: 1.4430x; 1.0336x over previous
//
#include <hip/hip_runtime.h>
#include <hip/hip_bf16.h>

typedef __attribute__((ext_vector_type(4))) float f32x4;
typedef __attribute__((ext_vector_type(16))) float f32x16;
typedef __attribute__((ext_vector_type(2))) unsigned int u32x2;
typedef __attribute__((ext_vector_type(4))) unsigned int u32x4;
typedef __attribute__((ext_vector_type(8))) __bf16 bf16x8;

// fp32 -> bf16 via HW cvt (RTNE)
__device__ inline unsigned short f2bf(float x) {
    return __builtin_bit_cast(unsigned short, (__bf16)x);
}
__device__ inline unsigned int pack2(float lo, float hi) {
    return (unsigned int)f2bf(lo) | ((unsigned int)f2bf(hi) << 16);
}
// load 8 fp32, convert to 8 packed bf16 (16B)
__device__ inline u32x4 cvt8(const float* __restrict__ p) {
    f32x4 a = *(const f32x4*)p;
    f32x4 b = *(const f32x4*)(p + 4);
    u32x4 r;
    r[0] = pack2(a[0], a[1]);
    r[1] = pack2(a[2], a[3]);
    r[2] = pack2(b[0], b[1]);
    r[3] = pack2(b[2], b[3]);
    return r;
}
__device__ inline bf16x8 ldfrag(const unsigned short* p) {
    u32x4 t = *(const u32x4*)p;
    return __builtin_bit_cast(bf16x8, t);
}

// ---------------- fp32 -> bf16 conversion kernels ----------------
__global__ __launch_bounds__(256) void cvt_bf16(
    const float* __restrict__ src, unsigned short* __restrict__ dst, int n8)
{
    for (int i = blockIdx.x * 256 + threadIdx.x; i < n8; i += gridDim.x * 256)
        *(u32x4*)(dst + (size_t)i * 8) = cvt8(src + (size_t)i * 8);
}
// 3 weight matrices (1024x1024 each) in one launch; grid (512, 3)
__global__ __launch_bounds__(256) void cvt_w3(
    const float* __restrict__ wq, const float* __restrict__ wk,
    const float* __restrict__ wv, unsigned short* __restrict__ dst)
{
    const float* s = blockIdx.y == 0 ? wq : (blockIdx.y == 1 ? wk : wv);
    unsigned short* d = dst + (size_t)blockIdx.y * 1048576;
    const int i = blockIdx.x * 256 + threadIdx.x;
    *(u32x4*)(d + (size_t)i * 8) = cvt8(s + (size_t)i * 8);
}

// ---------------- GEMM: C[8192][1024] = A * B^T (both bf16) ----------------
// m97 structure + T3 minimum-2-phase: double-buffered linear LDS staged via
// global_load_lds(16B); next tile's loads issued BEFORE current compute so
// the pre-barrier vmcnt(0) drain overlaps ds_read+MFMA instead of stalling.
// MODE 0: bf16 output (acc+bias)*alpha, row-major [token][d]
// MODE 1: fp32 output acc+bias+resid (output projection)
// MODE 2: bf16 output acc+bias, transposed per-head [b*16+h][dh][key'],
//         key' = key with bits 2<->3 swapped (pre-permuted for attn PV).
template<int MODE>
__global__ __launch_bounds__(256) void gemm_bt(
    const unsigned short* __restrict__ A, const unsigned short* __restrict__ Bw,
    const float* __restrict__ bias, const float* __restrict__ resid,
    void* __restrict__ Cp, float alpha)
{
    __shared__ unsigned short Al[2][128][32];
    __shared__ unsigned short Bl[2][128][32];
    const int tid = threadIdx.x;
    const int lane = tid & 63, w = tid >> 6;
    const int wr = w >> 1, wc = w & 1;
    const int m0 = blockIdx.x * 128, n0 = blockIdx.y * 128;
    const int fr = lane & 15, fq = lane >> 4;

    f32x4 acc[4][4] = {};

    auto stage = [&](int p, int k0) {
#pragma unroll
        for (int j = 0; j < 2; ++j) {
            const int f = (w * 2 + j) * 512 + lane * 8;   // halfword index
            const int r = f >> 5, c = f & 31;
            __builtin_amdgcn_global_load_lds(
                (const __attribute__((address_space(1))) void*)(A + (size_t)(m0 + r) * 1024 + k0 + c),
                (__attribute__((address_space(3))) void*)(&Al[p][0][0] + (w * 2 + j) * 512),
                16, 0, 0);
            __builtin_amdgcn_global_load_lds(
                (const __attribute__((address_space(1))) void*)(Bw + (size_t)(n0 + r) * 1024 + k0 + c),
                (__attribute__((address_space(3))) void*)(&Bl[p][0][0] + (w * 2 + j) * 512),
                16, 0, 0);
        }
    };

    stage(0, 0);
    __syncthreads();   // compiler drains vmcnt before barrier: tile 0 ready

    for (int k0 = 0; k0 < 1024; k0 += 32) {
        const int p = (k0 >> 5) & 1;
        if (k0 + 32 < 1024) stage(p ^ 1, k0 + 32);   // prefetch flies under compute

        bf16x8 af[4], bfv[4];
#pragma unroll
        for (int mt = 0; mt < 4; ++mt)
            af[mt] = ldfrag(&Al[p][wr * 64 + mt * 16 + fr][8 * fq]);
#pragma unroll
        for (int nt = 0; nt < 4; ++nt)
            bfv[nt] = ldfrag(&Bl[p][wc * 64 + nt * 16 + fr][8 * fq]);
#pragma unroll
        for (int mt = 0; mt < 4; ++mt)
#pragma unroll
            for (int nt = 0; nt < 4; ++nt)
                acc[mt][nt] = __builtin_amdgcn_mfma_f32_16x16x32_bf16(af[mt], bfv[nt], acc[mt][nt], 0, 0, 0);
        __syncthreads();   // drains next tile's loads; separates buffer reuse
    }

#pragma unroll
    for (int mt = 0; mt < 4; ++mt) {
#pragma unroll
        for (int nt = 0; nt < 4; ++nt) {
            const int col = n0 + wc * 64 + nt * 16 + fr;
            const float bb = bias[col];
            const int row0 = m0 + wr * 64 + mt * 16 + fq * 4;
            if (MODE == 2) {
                float v0 = acc[mt][nt][0] + bb, v1 = acc[mt][nt][1] + bb;
                float v2 = acc[mt][nt][2] + bb, v3 = acc[mt][nt][3] + bb;
                const int bb_ = row0 >> 11, key = row0 & 2047;
                const int key2 = (key & ~12) | ((key & 4) << 1) | ((key & 8) >> 1);
                const size_t idx = ((size_t)bb_ * 1024 + col) * 2048 + key2;
                u32x2 pv;
                pv[0] = pack2(v0, v1);
                pv[1] = pack2(v2, v3);
                *(u32x2*)((unsigned short*)Cp + idx) = pv;
            } else {
#pragma unroll
                for (int r = 0; r < 4; ++r) {
                    const size_t idx = (size_t)(row0 + r) * 1024 + col;
                    float v = (acc[mt][nt][r] + bb) * alpha;
                    if (MODE == 1) ((float*)Cp)[idx] = v + resid[idx];
                    else           ((unsigned short*)Cp)[idx] = f2bf(v);
                }
            }
        }
    }
}

// ---------------- Flash attention ----------------
// 4 waves x 64 q-rows/wave = 256 q-rows per block; KVBLK=64, ping-pong
// double-buffered K/V, ONE barrier per tile, T14 reg prefetch.
// XCD swizzle: blockIdx.x = bh&7 -> linear%8 constant per head -> all 8
// q-blocks of a head share one XCD's L2 (KV fetched ~once per head).
// Mask folded into QK^T via an extra MFMA (A = {mask_bf16,0,...}, B = ones).
// Denominator via mfma(P, ones): rowsums accumulate in os[] with the SAME
// register layout as o[] -> no shuffle/LDS reduce, no per-element adds.
// QK^T: mfma(A=K, B=Q) -> C[key][q]: q = lane&31, key = (r&3)+8*(r>>2)+4*hi.
// PV A-fragment = lane's own packed P words (V stored key-bit-2/3-permuted).
__global__ __launch_bounds__(256, 2) void attn_fwd(
    const unsigned short* __restrict__ Q, const unsigned short* __restrict__ K,
    const unsigned short* __restrict__ Vt_g, const int* __restrict__ mask,
    unsigned short* __restrict__ O)
{
    __shared__ unsigned short Kl[2][64][64];   // [buf][key][dh], XOR-swizzled
    __shared__ unsigned short Vl[2][64][64];   // [buf][dh][key'], XOR-swizzled
    __shared__ unsigned short mlb[2][64];      // mask, bf16 log2-domain additive
    const int tid = threadIdx.x, lane = tid & 63, w = tid >> 6;  // w in 0..3
    const int l31 = lane & 31, hi = lane >> 5;
    const int qb = blockIdx.y >> 3;
    const int bh = ((blockIdx.y & 7) << 3) | blockIdx.x;   // XCD = bh&7
    const int q0 = qb * 256;
    const int b = bh >> 4;
    const size_t rowbase = (size_t)b * 2048;
    const int hoff = (bh & 15) * 64;
    const size_t vbase = (size_t)bh * 64 * 2048;

    const u32x4 onesu = {0x3F803F80u, 0x3F803F80u, 0x3F803F80u, 0x3F803F80u};
    const bf16x8 vones = __builtin_bit_cast(bf16x8, onesu);

    // swizzle keys for fragment-read rows r = t*32 + l31 (t = 0,1)
    const int sw0 = (((l31) ^ (l31 >> 3)) & 7) << 3;
    const int sw1 = (((l31) ^ ((l31 >> 3) + 4)) & 7) << 3;

    // Q fragments: group a covers q-row q0 + w*64 + a*32 + l31
    bf16x8 aq[2][4];
#pragma unroll
    for (int a = 0; a < 2; ++a) {
        const unsigned short* qp = Q + (rowbase + q0 + w * 64 + a * 32 + l31) * 1024 + hoff + hi * 8;
#pragma unroll
        for (int kk = 0; kk < 4; ++kk) aq[a][kk] = ldfrag(qp + kk * 16);
    }
    f32x16 o[2][2] = {};
    f32x16 os[2] = {};   // denominator accumulators (rowsums of P)

    // staging: 256 threads x 2 chunks of 16B cover one 64x64 bf16 tile
    int srow[2], scol[2];
#pragma unroll
    for (int i = 0; i < 2; ++i) {
        int e = (i * 256 + tid) * 8;
        srow[i] = e >> 6;
        scol[i] = e & 63;
    }

    // prologue: tile 0 into regs
    u32x4 kpre[2], vpre[2];
    int mpre = 0;
#pragma unroll
    for (int i = 0; i < 2; ++i) {
        kpre[i] = *(const u32x4*)(K + (rowbase + srow[i]) * 1024 + hoff + scol[i]);
        vpre[i] = *(const u32x4*)(Vt_g + vbase + (size_t)srow[i] * 2048 + scol[i]);
    }
    if (tid < 64) mpre = mask[rowbase + tid];

    for (int kb = 0, it = 0; kb < 2048; kb += 64, ++it) {
        const int p = it & 1;
#pragma unroll
        for (int i = 0; i < 2; ++i) {
            const int cs = scol[i] ^ (((srow[i] ^ (srow[i] >> 3)) & 7) << 3);
            *(u32x4*)&Kl[p][srow[i]][cs] = kpre[i];
            *(u32x4*)&Vl[p][srow[i]][cs] = vpre[i];
        }
        if (tid < 64) mlb[p][tid] = f2bf(mpre == 0 ? -30000.0f : 0.0f);
        // T14: issue next tile's global loads; they fly during barrier+compute
        if (kb + 64 < 2048) {
#pragma unroll
            for (int i = 0; i < 2; ++i) {
                kpre[i] = *(const u32x4*)(K + (rowbase + kb + 64 + srow[i]) * 1024 + hoff + scol[i]);
                vpre[i] = *(const u32x4*)(Vt_g + vbase + (size_t)srow[i] * 2048 + kb + 64 + scol[i]);
            }
            if (tid < 64) mpre = mask[rowbase + kb + 64 + tid];
        }
        __syncthreads();   // buf p ready (single barrier per tile)

#pragma unroll
        for (int t = 0; t < 2; ++t) {
            const int swt = t ? sw1 : sw0;
            // mask fragment: A[key=l31][k=0] = mask_bf (hi==0 lanes), else 0
            const unsigned int mv = (hi == 0) ? (unsigned int)mlb[p][t * 32 + l31] : 0u;
            const u32x4 mfu = {mv, 0u, 0u, 0u};
            const bf16x8 kfm = __builtin_bit_cast(bf16x8, mfu);

            // QK^T for both q-groups, K-fragments register-reused
            f32x16 z0 = {}, z1 = {};
            __builtin_amdgcn_s_setprio(1);
            z0 = __builtin_amdgcn_mfma_f32_32x32x16_bf16(kfm, vones, z0, 0, 0, 0);
            z1 = __builtin_amdgcn_mfma_f32_32x32x16_bf16(kfm, vones, z1, 0, 0, 0);
#pragma unroll
            for (int kk = 0; kk < 4; ++kk) {
                bf16x8 kf = ldfrag(&Kl[p][t * 32 + l31][(kk * 16 + hi * 8) ^ swt]);
                z0 = __builtin_amdgcn_mfma_f32_32x32x16_bf16(kf, aq[0][kk], z0, 0, 0, 0);
                z1 = __builtin_amdgcn_mfma_f32_32x32x16_bf16(kf, aq[1][kk], z1, 0, 0, 0);
            }
            __builtin_amdgcn_s_setprio(0);

            // p = exp2(z) (mask already added in-MFMA); pack per 4-key group
            unsigned int pk[2][4][2];
#pragma unroll
            for (int g = 0; g < 4; ++g) {
                {
                    float p0 = __builtin_amdgcn_exp2f(z0[g * 4 + 0]);
                    float p1 = __builtin_amdgcn_exp2f(z0[g * 4 + 1]);
                    float p2 = __builtin_amdgcn_exp2f(z0[g * 4 + 2]);
                    float p3 = __builtin_amdgcn_exp2f(z0[g * 4 + 3]);
                    pk[0][g][0] = pack2(p0, p1);
                    pk[0][g][1] = pack2(p2, p3);
                }
                {
                    float p0 = __builtin_amdgcn_exp2f(z1[g * 4 + 0]);
                    float p1 = __builtin_amdgcn_exp2f(z1[g * 4 + 1]);
                    float p2 = __builtin_amdgcn_exp2f(z1[g * 4 + 2]);
                    float p3 = __builtin_amdgcn_exp2f(z1[g * 4 + 3]);
                    pk[1][g][0] = pack2(p0, p1);
                    pk[1][g][1] = pack2(p2, p3);
                }
            }

            // PV: V-fragments register-reused across both q-groups.
            // os += P * ones -> per-q rowsums (denominator) on the MFMA pipe.
#pragma unroll
            for (int half = 0; half < 2; ++half) {
                const int c = t * 2 + half, G = half * 2;
                u32x4 fu0 = {pk[0][G][0], pk[0][G][1], pk[0][G + 1][0], pk[0][G + 1][1]};
                u32x4 fu1 = {pk[1][G][0], pk[1][G][1], pk[1][G + 1][0], pk[1][G + 1][1]};
                bf16x8 pf0 = __builtin_bit_cast(bf16x8, fu0);
                bf16x8 pf1 = __builtin_bit_cast(bf16x8, fu1);
                __builtin_amdgcn_s_setprio(1);
#pragma unroll
                for (int dt = 0; dt < 2; ++dt) {
                    const int swd = dt ? sw1 : sw0;
                    bf16x8 vb = ldfrag(&Vl[p][dt * 32 + l31][(c * 16 + hi * 8) ^ swd]);
                    o[0][dt] = __builtin_amdgcn_mfma_f32_32x32x16_bf16(pf0, vb, o[0][dt], 0, 0, 0);
                    o[1][dt] = __builtin_amdgcn_mfma_f32_32x32x16_bf16(pf1, vb, o[1][dt], 0, 0, 0);
                }
                os[0] = __builtin_amdgcn_mfma_f32_32x32x16_bf16(pf0, vones, os[0], 0, 0, 0);
                os[1] = __builtin_amdgcn_mfma_f32_32x32x16_bf16(pf1, vones, os[1], 0, 0, 0);
                __builtin_amdgcn_s_setprio(0);
            }
        }
    }

    // os[a][reg] = full denominator for the q-row of that reg (same layout
    // as o) -- normalize directly, no cross-lane reduce needed.
#pragma unroll
    for (int a = 0; a < 2; ++a)
#pragma unroll
        for (int g = 0; g < 4; ++g)
#pragma unroll
            for (int j = 0; j < 4; ++j) {
                const float inv = 1.0f / os[a][g * 4 + j];
                const size_t row = rowbase + q0 + w * 64 + a * 32 + g * 8 + hi * 4 + j;
#pragma unroll
                for (int dt = 0; dt < 2; ++dt)
                    O[row * 1024 + hoff + dt * 32 + l31] = f2bf(o[a][dt][g * 4 + j] * inv);
            }
}

// In-place LayerNorm over last dim (1024), one row per block.
__global__ __launch_bounds__(256) void ln_inplace(
    float* __restrict__ X, const float* __restrict__ gamma, const float* __restrict__ beta)
{
    __shared__ float red[8];
    const int tid = threadIdx.x, lane = tid & 63, w = tid >> 6;
    float* p = X + (size_t)blockIdx.x * 1024;
    f32x4 v = *((const f32x4*)p + tid);
    float s = v[0] + v[1] + v[2] + v[3];
    float s2 = v[0] * v[0] + v[1] * v[1] + v[2] * v[2] + v[3] * v[3];
#pragma unroll
    for (int d = 1; d < 64; d <<= 1) {
        s += __shfl_xor(s, d);
        s2 += __shfl_xor(s2, d);
    }
    if (lane == 0) { red[w] = s; red[4 + w] = s2; }
    __syncthreads();
    s = red[0] + red[1] + red[2] + red[3];
    s2 = red[4] + red[5] + red[6] + red[7];
    const float mu = s * (1.0f / 1024.0f);
    const float var = s2 * (1.0f / 1024.0f) - mu * mu;
    const float rstd = rsqrtf(var + 1e-5f);
    f32x4 g = *((const f32x4*)gamma + tid);
    f32x4 be = *((const f32x4*)beta + tid);
    f32x4 out;
#pragma unroll
    for (int j = 0; j < 4; ++j) out[j] = (v[j] - mu) * rstd * g[j] + be[j];
    *((f32x4*)p + tid) = out;
}

extern "C" void kernel_launch(void* const* d_in, const int* in_sizes, int n_in,
                              void* d_out, int out_size, void* d_ws, size_t ws_size,
                              hipStream_t stream) {
    const float* query = (const float*)d_in[0];
    const float* key_  = (const float*)d_in[1];
    const float* value = (const float*)d_in[2];
    const int*   mask  = (const int*)d_in[3];
    const float* Wq = (const float*)d_in[4];
    const float* bq = (const float*)d_in[5];
    const float* Wk = (const float*)d_in[6];
    const float* bk = (const float*)d_in[7];
    const float* Wv = (const float*)d_in[8];
    const float* bv = (const float*)d_in[9];
    const float* Wo = (const float*)d_in[10];
    const float* bo = (const float*)d_in[11];
    const float* gamma = (const float*)d_in[12];
    const float* beta  = (const float*)d_in[13];

    const size_t MD = (size_t)8192 * 1024;
    unsigned short* Qb  = (unsigned short*)d_ws;
    unsigned short* Kb  = Qb + MD;
    unsigned short* Vtb = Kb + MD;   // permuted V^T: [b*16+h][dh][key bits2/3 swapped]
    unsigned short* Ab  = Vtb + MD;  // (a) staging buf for bf16 inputs, (b) attn out
    float* out = (float*)d_out;
    // weights (bf16) live in d_out scratch until gemmO overwrites it
    unsigned short* W16 = (unsigned short*)d_out;     // Wq @0, Wk @1M, Wv @2M elems
    unsigned short* Wo16 = Vtb;                       // after attn, Vtb is free

    dim3 gg(64, 8);
    const float qscale = 0.125f * 1.4426950408889634f;  // 1/sqrt(64) * log2(e)

    // bf16 weights for QKV projections -> d_out scratch
    cvt_w3<<<dim3(512, 3), 256, 0, stream>>>(Wq, Wk, Wv, W16);
    cvt_bf16<<<2048, 256, 0, stream>>>(query, Ab, 1048576);
    gemm_bt<0><<<gg, 256, 0, stream>>>(Ab, W16, bq, nullptr, Qb, qscale);
    cvt_bf16<<<2048, 256, 0, stream>>>(key_, Ab, 1048576);
    gemm_bt<0><<<gg, 256, 0, stream>>>(Ab, W16 + 1048576, bk, nullptr, Kb, 1.0f);
    cvt_bf16<<<2048, 256, 0, stream>>>(value, Ab, 1048576);
    gemm_bt<2><<<gg, 256, 0, stream>>>(Ab, W16 + 2097152, bv, nullptr, Vtb, 1.0f);

    attn_fwd<<<dim3(8, 64), 256, 0, stream>>>(Qb, Kb, Vtb, mask, Ab);

    cvt_bf16<<<512, 256, 0, stream>>>(Wo, Wo16, 131072);
    gemm_bt<1><<<gg, 256, 0, stream>>>(Ab, Wo16, bo, query, out, 1.0f);
    ln_inplace<<<8192, 256, 0, stream>>>(out, gamma, beta);
}